// Round 1
// baseline (674.213 us; speedup 1.0000x reference)
//
#include <hip/hip_runtime.h>
#include <hip/hip_bf16.h>

// Shapes (fixed by the reference)
#define NB   32
#define C    256
#define CI   128
#define HW   4096   // 64*64
#define NHW  131072 // NB*HW

// ---------------------------------------------------------------------------
// K1: per-(n,c) spatial sums of x.  One block per (n*C+c), 256 threads.
__global__ __launch_bounds__(256) void k_colsum(const float* __restrict__ x,
                                                float* __restrict__ s) {
    const int bc = blockIdx.x;
    const float4* p4 = (const float4*)(x + (size_t)bc * HW);
    const int tid = threadIdx.x;
    float acc = 0.f;
    for (int i = tid; i < HW / 4; i += 256) {
        float4 v = p4[i];
        acc += v.x + v.y + v.z + v.w;
    }
    for (int off = 32; off; off >>= 1) acc += __shfl_down(acc, off, 64);
    __shared__ float red[4];
    if ((tid & 63) == 0) red[tid >> 6] = acc;
    __syncthreads();
    if (tid == 0) s[bc] = red[0] + red[1] + red[2] + red[3];
}

// ---------------------------------------------------------------------------
// K2a: per-batch attention matrix A_n [128x128] from channel sums.
// theta_s[d] = w_theta[d,:]. (s/16) + 256*b_theta[d]; same for phi.
// A[c,d] = softmax_d( th[c]*ph[d]*128^-0.5 ).  Also q[c] = A[c,:] . b_g.
__global__ __launch_bounds__(128) void k_attn(const float* __restrict__ s,
        const float* __restrict__ w_theta, const float* __restrict__ b_theta,
        const float* __restrict__ w_phi,  const float* __restrict__ b_phi,
        const float* __restrict__ b_g,
        float* __restrict__ A, float* __restrict__ q) {
    const int n = blockIdx.x;
    const int d = threadIdx.x;  // 0..127
    __shared__ float sh_s[C];
    __shared__ float th[CI], ph[CI];
    __shared__ float smax[2], smin[2], red[2];

    sh_s[d]       = s[n * C + d];
    sh_s[d + 128] = s[n * C + d + 128];
    __syncthreads();

    float td = 0.f, pd = 0.f;
    for (int c = 0; c < C; ++c) {
        float sv = sh_s[c] * (1.f / 16.f);
        td += w_theta[d * C + c] * sv;
        pd += w_phi[d * C + c] * sv;
    }
    td += 256.f * b_theta[d];
    pd += 256.f * b_phi[d];
    th[d] = td * 0.08838834764831845f;  // 128^-0.5 folded into theta side
    ph[d] = pd;
    __syncthreads();

    // global max/min of ph (softmax max is th[c]*phmax or th[c]*phmin)
    float pmax = ph[d], pmin = ph[d];
    for (int off = 32; off; off >>= 1) {
        pmax = fmaxf(pmax, __shfl_xor(pmax, off, 64));
        pmin = fminf(pmin, __shfl_xor(pmin, off, 64));
    }
    if ((d & 63) == 0) { smax[d >> 6] = pmax; smin[d >> 6] = pmin; }
    __syncthreads();
    pmax = fmaxf(smax[0], smax[1]);
    pmin = fminf(smin[0], smin[1]);

    const float bg = b_g[d];
    for (int c = 0; c < CI; ++c) {
        float a_c = th[c];
        float m = (a_c >= 0.f) ? a_c * pmax : a_c * pmin;
        float e = expf(a_c * ph[d] - m);
        float ssum = e;
        for (int off = 32; off; off >>= 1) ssum += __shfl_xor(ssum, off, 64);
        if ((d & 63) == 0) red[d >> 6] = ssum;
        __syncthreads();
        float av = e / (red[0] + red[1]);
        A[((size_t)n * CI + c) * CI + d] = av;
        __syncthreads();              // protect red[] before reuse
        float qv = av * bg;
        for (int off = 32; off; off >>= 1) qv += __shfl_xor(qv, off, 64);
        if ((d & 63) == 0) red[d >> 6] = qv;
        __syncthreads();
        if (d == 0) q[n * CI + c] = red[0] + red[1];
        __syncthreads();              // protect red[] for next iteration
    }
}

// ---------------------------------------------------------------------------
// K2b: W_n[o,d] = sum_c w_out[o,c] * A_n[c,d];  cvec[n,o] = w_out[o,:].q_n + b_out[o]
__global__ __launch_bounds__(128) void k_W(const float* __restrict__ w_out,
        const float* __restrict__ A, const float* __restrict__ q,
        const float* __restrict__ b_out,
        float* __restrict__ W, float* __restrict__ cvec) {
    const int n = blockIdx.x >> 8, o = blockIdx.x & 255, d = threadIdx.x;
    float acc = 0.f;
    for (int c = 0; c < CI; ++c)
        acc += w_out[o * CI + c] * A[((size_t)n * CI + c) * CI + d];
    W[((size_t)n * C + o) * CI + d] = acc;
    if (d == 0) {
        float cv = 0.f;
        for (int c = 0; c < CI; ++c) cv += w_out[o * CI + c] * q[n * CI + c];
        cvec[n * C + o] = cv + b_out[o];
    }
}

// ---------------------------------------------------------------------------
// K2c: M_n[o,c2] = sum_d W_n[o,d] * w_g[d,c2]
__global__ __launch_bounds__(256) void k_M(const float* __restrict__ W,
        const float* __restrict__ w_g, float* __restrict__ M) {
    const int n = blockIdx.x >> 8, o = blockIdx.x & 255, c2 = threadIdx.x;
    const float* Wp = W + ((size_t)n * C + o) * CI;
    float acc = 0.f;
    for (int d = 0; d < CI; ++d) acc += Wp[d] * w_g[d * C + c2];
    M[((size_t)(n * C + o)) * C + c2] = acc;
}

// ---------------------------------------------------------------------------
// K3: p[n] = M_n @ x[n] + c_n  (256x4096 = 256x256 @ 256x4096), p -> d_out (fp32)
// plus fused per-channel sum / sumsq accumulation for BN.
#define BM 64
#define BN 64
#define BK 16
__global__ __launch_bounds__(256) void k_gemm(const float* __restrict__ x,
        const float* __restrict__ M, const float* __restrict__ cvec,
        float* __restrict__ pout,
        float* __restrict__ bnsum, float* __restrict__ bnsumsq) {
    const int n  = blockIdx.y;
    const int ot = (blockIdx.x >> 6) * BM;   // 4 o-tiles
    const int tt = (blockIdx.x & 63) * BN;   // 64 t-tiles
    const float* Mb = M + (size_t)n * C * C;
    const float* xb = x + (size_t)n * C * HW;

    __shared__ float sA[BK][BM];   // [k][o]
    __shared__ float sB[BK][BN];   // [k][t]

    const int tid = threadIdx.x;
    const int ty = tid >> 4, tx = tid & 15;
    float acc[4][4] = {};

    for (int k0 = 0; k0 < C; k0 += BK) {
        {   // M tile: 64 rows x 16 k, float4 per thread
            int row = tid >> 2;
            int kq  = (tid & 3) << 2;
            const float4 v = *(const float4*)&Mb[(size_t)(ot + row) * C + k0 + kq];
            sA[kq + 0][row] = v.x; sA[kq + 1][row] = v.y;
            sA[kq + 2][row] = v.z; sA[kq + 3][row] = v.w;
        }
        {   // x tile: 16 k-rows x 64 t, float4 per thread
            int krow = tid >> 4;
            int tq   = (tid & 15) << 2;
            const float4 v = *(const float4*)&xb[(size_t)(k0 + krow) * HW + tt + tq];
            *(float4*)&sB[krow][tq] = v;
        }
        __syncthreads();
#pragma unroll
        for (int kk = 0; kk < BK; ++kk) {
            float a[4], b[4];
#pragma unroll
            for (int i = 0; i < 4; ++i) a[i] = sA[kk][ty * 4 + i];
#pragma unroll
            for (int j = 0; j < 4; ++j) b[j] = sB[kk][tx * 4 + j];
#pragma unroll
            for (int i = 0; i < 4; ++i)
#pragma unroll
                for (int j = 0; j < 4; ++j) acc[i][j] += a[i] * b[j];
        }
        __syncthreads();
    }

    // epilogue: add bias, store p, accumulate BN statistics
#pragma unroll
    for (int i = 0; i < 4; ++i) {
        const int o = ot + ty * 4 + i;
        const float cv = cvec[n * C + o];
        float4 v;
        v.x = acc[i][0] + cv; v.y = acc[i][1] + cv;
        v.z = acc[i][2] + cv; v.w = acc[i][3] + cv;
        *(float4*)&pout[((size_t)n * C + o) * HW + tt + tx * 4] = v;
        float s0 = v.x + v.y + v.z + v.w;
        float s1 = v.x * v.x + v.y * v.y + v.z * v.z + v.w * v.w;
        for (int off = 1; off < 16; off <<= 1) {
            s0 += __shfl_xor(s0, off, 64);
            s1 += __shfl_xor(s1, off, 64);
        }
        if (tx == 0) {
            atomicAdd(&bnsum[o], s0);
            atomicAdd(&bnsumsq[o], s1);
        }
    }
}

// ---------------------------------------------------------------------------
// K4: finalize BN affine params.
__global__ __launch_bounds__(256) void k_bnfin(const float* __restrict__ bnsum,
        const float* __restrict__ bnsumsq, const float* __restrict__ gamma,
        const float* __restrict__ beta,
        float* __restrict__ scale, float* __restrict__ shift) {
    const int o = threadIdx.x;
    const float inv = 1.f / (float)NHW;
    float mean = bnsum[o] * inv;
    float var  = bnsumsq[o] * inv - mean * mean;
    float sc   = gamma[o] * rsqrtf(var + 1e-5f);
    scale[o] = sc;
    shift[o] = beta[o] - mean * sc;
}

// ---------------------------------------------------------------------------
// K5: out = x + scale[c]*p + shift[c]   (in-place on d_out which holds p)
__global__ __launch_bounds__(256) void k_final(const float* __restrict__ x,
        float* __restrict__ out, const float* __restrict__ scale,
        const float* __restrict__ shift) {
    const size_t total4 = (size_t)NB * C * HW / 4;
    size_t i = (size_t)blockIdx.x * 256 + threadIdx.x;
    const size_t stride = (size_t)gridDim.x * 256;
    for (; i < total4; i += stride) {
        const int c = (int)((i >> 10) & 255);  // (i*4 / 4096) % 256
        const float sc = scale[c], sh = shift[c];
        float4 xv = ((const float4*)x)[i];
        float4 pv = ((float4*)out)[i];
        float4 r;
        r.x = xv.x + sc * pv.x + sh;
        r.y = xv.y + sc * pv.y + sh;
        r.z = xv.z + sc * pv.z + sh;
        r.w = xv.w + sc * pv.w + sh;
        ((float4*)out)[i] = r;
    }
}

// ---------------------------------------------------------------------------
extern "C" void kernel_launch(void* const* d_in, const int* in_sizes, int n_in,
                              void* d_out, int out_size, void* d_ws, size_t ws_size,
                              hipStream_t stream) {
    const float* x       = (const float*)d_in[0];
    const float* w_theta = (const float*)d_in[1];
    const float* b_theta = (const float*)d_in[2];
    const float* w_phi   = (const float*)d_in[3];
    const float* b_phi   = (const float*)d_in[4];
    const float* w_g     = (const float*)d_in[5];
    const float* b_g     = (const float*)d_in[6];
    const float* w_out   = (const float*)d_in[7];
    const float* b_out   = (const float*)d_in[8];
    const float* gamma   = (const float*)d_in[9];
    const float* beta    = (const float*)d_in[10];
    float* out = (float*)d_out;
    float* ws  = (float*)d_ws;

    // workspace layout (floats) — ~14.8 MB total
    float* s      = ws;                  // 32*256
    float* A      = s + NB * C;          // 32*128*128
    float* q      = A + NB * CI * CI;    // 32*128
    float* W      = q + NB * CI;         // 32*256*128
    float* M      = W + NB * C * CI;     // 32*256*256
    float* cvec   = M + NB * C * C;      // 32*256
    float* bnsum  = cvec + NB * C;       // 256
    float* bnsumsq= bnsum + C;           // 256
    float* scale  = bnsumsq + C;         // 256
    float* shift  = scale + C;           // 256

    k_colsum<<<NB * C, 256, 0, stream>>>(x, s);
    k_attn<<<NB, CI, 0, stream>>>(s, w_theta, b_theta, w_phi, b_phi, b_g, A, q);
    k_W<<<NB * C, CI, 0, stream>>>(w_out, A, q, b_out, W, cvec);
    k_M<<<NB * C, C, 0, stream>>>(W, w_g, M);
    hipMemsetAsync(bnsum, 0, 2 * C * sizeof(float), stream);
    k_gemm<<<dim3(256, NB), 256, 0, stream>>>(x, M, cvec, out, bnsum, bnsumsq);
    k_bnfin<<<1, C, 0, stream>>>(bnsum, bnsumsq, gamma, beta, scale, shift);
    k_final<<<32768, 256, 0, stream>>>(x, out, scale, shift);
}

// Round 2
// 485.363 us; speedup vs baseline: 1.3891x; 1.3891x over previous
//
#include <hip/hip_runtime.h>
#include <hip/hip_bf16.h>

#define NB   32
#define C    256
#define CI   128
#define HW   4096
#define NHW  131072

typedef __attribute__((ext_vector_type(8))) short short8;
typedef __attribute__((ext_vector_type(4))) float floatx4;

__device__ __forceinline__ unsigned short f2bf(float f) {
    unsigned int u = __float_as_uint(f);
    return (unsigned short)((u + 0x7fffu + ((u >> 16) & 1u)) >> 16);
}

// ---------------------------------------------------------------------------
// K0: fused cast+transpose (x fp32 [n][c][t] -> xT bf16 [n][t][c]) + channel sums.
// grid (64 t-tiles, 4 c-tiles, 32 n), block 256.
__global__ __launch_bounds__(256) void k_prep(const float* __restrict__ x,
        unsigned short* __restrict__ xT, float* __restrict__ s) {
    const int n = blockIdx.z, c0 = blockIdx.y * 64, t0 = blockIdx.x * 64;
    __shared__ float sA[64][68];
    const int tid = threadIdx.x;
    const int cr = tid >> 4;          // 0..15
    const int tq = (tid & 15) * 4;    // 0..60
#pragma unroll
    for (int pass = 0; pass < 4; ++pass) {
        const int c = cr + pass * 16;
        const float4 v = *(const float4*)&x[((size_t)n * C + c0 + c) * HW + t0 + tq];
        const int swz = ((c >> 3) & 7) * 8;
        *(float4*)&sA[c][tq ^ swz] = v;
        float ps = v.x + v.y + v.z + v.w;
        for (int off = 1; off < 16; off <<= 1) ps += __shfl_xor(ps, off, 64);
        if ((tid & 15) == 0) atomicAdd(&s[n * C + c0 + c], ps);
    }
    __syncthreads();
    // write xT rows: 32 t-rows per pass, 8 threads/row, 8 c each
    const int tr = tid >> 3;          // 0..31
    const int cc = (tid & 7) * 8;     // 0..56
#pragma unroll
    for (int pass = 0; pass < 2; ++pass) {
        const int t = tr + pass * 32;
        unsigned int w[4];
#pragma unroll
        for (int jj = 0; jj < 4; ++jj) {
            const int ca = cc + 2 * jj, cb = cc + 2 * jj + 1;
            unsigned short lo = f2bf(sA[ca][t ^ (((ca >> 3) & 7) * 8)]);
            unsigned short hi = f2bf(sA[cb][t ^ (((cb >> 3) & 7) * 8)]);
            w[jj] = (unsigned int)lo | ((unsigned int)hi << 16);
        }
        uint4 u4; u4.x = w[0]; u4.y = w[1]; u4.z = w[2]; u4.w = w[3];
        *(uint4*)&xT[((size_t)n * HW + t0 + t) * C + c0 + cc] = u4;
    }
}

// ---------------------------------------------------------------------------
// K1: theta/phi vectors per batch + ph max/min. grid 32, block 128.
__global__ __launch_bounds__(128) void k_thph(const float* __restrict__ s,
        const float* __restrict__ w_theta, const float* __restrict__ b_theta,
        const float* __restrict__ w_phi,  const float* __restrict__ b_phi,
        float* __restrict__ th, float* __restrict__ ph, float* __restrict__ pm) {
    const int n = blockIdx.x, d = threadIdx.x;
    __shared__ float sh_s[C];
    __shared__ float smax[2], smin[2];
    sh_s[d]       = s[n * C + d];
    sh_s[d + 128] = s[n * C + d + 128];
    __syncthreads();
    float td = 0.f, pd = 0.f;
    for (int c = 0; c < C; ++c) {
        const float sv = sh_s[c] * (1.f / 16.f);
        td += w_theta[d * C + c] * sv;
        pd += w_phi[d * C + c] * sv;
    }
    td = (td + 256.f * b_theta[d]) * 0.08838834764831845f;
    pd = pd + 256.f * b_phi[d];
    th[n * CI + d] = td;
    ph[n * CI + d] = pd;
    float pmax = pd, pmin = pd;
    for (int off = 32; off; off >>= 1) {
        pmax = fmaxf(pmax, __shfl_xor(pmax, off, 64));
        pmin = fminf(pmin, __shfl_xor(pmin, off, 64));
    }
    if ((d & 63) == 0) { smax[d >> 6] = pmax; smin[d >> 6] = pmin; }
    __syncthreads();
    if (d == 0) {
        pm[n * 2 + 0] = fmaxf(smax[0], smax[1]);
        pm[n * 2 + 1] = fminf(smin[0], smin[1]);
    }
}

// ---------------------------------------------------------------------------
// K2: one softmax row of A per one-wave block. grid NB*CI, block 64.
__global__ __launch_bounds__(64) void k_arow(const float* __restrict__ th,
        const float* __restrict__ ph, const float* __restrict__ pm,
        const float* __restrict__ b_g,
        float* __restrict__ A, float* __restrict__ q) {
    const int n = blockIdx.x >> 7, c = blockIdx.x & 127, lane = threadIdx.x;
    const float thc = th[n * CI + c];
    const float2 phv = *(const float2*)&ph[n * CI + lane * 2];
    const float m = (thc >= 0.f) ? thc * pm[n * 2] : thc * pm[n * 2 + 1];
    float e0 = __expf(thc * phv.x - m);
    float e1 = __expf(thc * phv.y - m);
    float z = e0 + e1;
    for (int off = 32; off; off >>= 1) z += __shfl_xor(z, off, 64);
    const float inv = 1.f / z;
    e0 *= inv; e1 *= inv;
    float2 av; av.x = e0; av.y = e1;
    *(float2*)&A[((size_t)n * CI + c) * CI + lane * 2] = av;
    const float2 bg = *(const float2*)&b_g[lane * 2];
    float qv = e0 * bg.x + e1 * bg.y;
    for (int off = 32; off; off >>= 1) qv += __shfl_xor(qv, off, 64);
    if (lane == 0) q[n * CI + c] = qv;
}

// ---------------------------------------------------------------------------
// K3: W_n[o,d] = sum_c w_out[o,c] * A_n[c,d];  cvec[n,o] = w_out[o,:].q_n + b_out[o]
__global__ __launch_bounds__(128) void k_W(const float* __restrict__ w_out,
        const float* __restrict__ A, const float* __restrict__ q,
        const float* __restrict__ b_out,
        float* __restrict__ W, float* __restrict__ cvec) {
    const int n = blockIdx.x >> 8, o = blockIdx.x & 255, d = threadIdx.x;
    float acc = 0.f;
    for (int c = 0; c < CI; ++c)
        acc += w_out[o * CI + c] * A[((size_t)n * CI + c) * CI + d];
    W[((size_t)n * C + o) * CI + d] = acc;
    if (d == 0) {
        float cv = 0.f;
        for (int c = 0; c < CI; ++c) cv += w_out[o * CI + c] * q[n * CI + c];
        cvec[n * C + o] = cv + b_out[o];
    }
}

// ---------------------------------------------------------------------------
// K4: M_n[o,c2] = sum_d W_n[o,d] * w_g[d,c2]  (fp32 + bf16 copies)
__global__ __launch_bounds__(256) void k_M(const float* __restrict__ W,
        const float* __restrict__ w_g, float* __restrict__ M,
        unsigned short* __restrict__ Mb16) {
    const int n = blockIdx.x >> 8, o = blockIdx.x & 255, c2 = threadIdx.x;
    const float* Wp = W + ((size_t)n * C + o) * CI;
    float acc = 0.f;
    for (int d = 0; d < CI; ++d) acc += Wp[d] * w_g[d * C + c2];
    M[((size_t)n * C + o) * C + c2] = acc;
    Mb16[((size_t)n * C + o) * C + c2] = f2bf(acc);
}

// ---------------------------------------------------------------------------
// K5: MFMA GEMM  p[n] = M_n @ x[n] + cvec, fp32 out to d_out.
// No LDS: A/B fragments loaded straight from L2 (K-contiguous layouts).
// grid (64, 32): bx&31 = t-tile(128), bx>>5 = o-tile(128). 4 waves, 2x2 of 64x64.
__global__ __launch_bounds__(256) void k_gemm_mfma(
        const unsigned short* __restrict__ xT,   // [n][4096][256] bf16
        const unsigned short* __restrict__ Mb,   // [n][256][256] bf16
        const float* __restrict__ cvec,
        float* __restrict__ pout) {
    const int n  = blockIdx.y;
    const int tt = (blockIdx.x & 31) * 128;
    const int ot = (blockIdx.x >> 5) * 128;
    const int wave = threadIdx.x >> 6, lane = threadIdx.x & 63;
    const int wm = (wave >> 1) * 64, wn = (wave & 1) * 64;
    const int l15 = lane & 15, q8 = (lane >> 4) * 8;

    const unsigned short* Abase = Mb + ((size_t)n * C + ot + wm + l15) * C + q8;
    const unsigned short* Bbase = xT + ((size_t)n * HW + tt + wn + l15) * C + q8;

    floatx4 acc[4][4] = {};
    for (int k0 = 0; k0 < C; k0 += 32) {
        short8 a[4], b[4];
#pragma unroll
        for (int i = 0; i < 4; ++i)
            a[i] = *(const short8*)(Abase + (size_t)i * 16 * C + k0);
#pragma unroll
        for (int j = 0; j < 4; ++j)
            b[j] = *(const short8*)(Bbase + (size_t)j * 16 * C + k0);
#pragma unroll
        for (int i = 0; i < 4; ++i)
#pragma unroll
            for (int j = 0; j < 4; ++j)
                acc[i][j] = __builtin_amdgcn_mfma_f32_16x16x32_bf16(
                    a[i], b[j], acc[i][j], 0, 0, 0);
    }
    const int quad = lane >> 4;
#pragma unroll
    for (int i = 0; i < 4; ++i) {
        const int rowb = ot + wm + i * 16 + quad * 4;
#pragma unroll
        for (int r = 0; r < 4; ++r) {
            const float cv = cvec[n * C + rowb + r];
            float* orow = pout + ((size_t)n * C + rowb + r) * HW + tt + wn + l15;
#pragma unroll
            for (int j = 0; j < 4; ++j)
                orow[j * 16] = acc[i][j][r] + cv;
        }
    }
}

// ---------------------------------------------------------------------------
// K5-fallback: fp32 SGEMM (round-1 kernel, no atomics) if ws too small for xT.
#define BM 64
#define BN 64
#define BK 16
__global__ __launch_bounds__(256) void k_gemm_f32(const float* __restrict__ x,
        const float* __restrict__ M, const float* __restrict__ cvec,
        float* __restrict__ pout) {
    const int n  = blockIdx.y;
    const int ot = (blockIdx.x >> 6) * BM;
    const int tt = (blockIdx.x & 63) * BN;
    const float* Mb = M + (size_t)n * C * C;
    const float* xb = x + (size_t)n * C * HW;
    __shared__ float sA[BK][BM];
    __shared__ float sB[BK][BN];
    const int tid = threadIdx.x;
    const int ty = tid >> 4, tx = tid & 15;
    float acc[4][4] = {};
    for (int k0 = 0; k0 < C; k0 += BK) {
        {
            int row = tid >> 2, kq = (tid & 3) << 2;
            const float4 v = *(const float4*)&Mb[(size_t)(ot + row) * C + k0 + kq];
            sA[kq + 0][row] = v.x; sA[kq + 1][row] = v.y;
            sA[kq + 2][row] = v.z; sA[kq + 3][row] = v.w;
        }
        {
            int krow = tid >> 4, tq2 = (tid & 15) << 2;
            const float4 v = *(const float4*)&xb[(size_t)(k0 + krow) * HW + tt + tq2];
            *(float4*)&sB[krow][tq2] = v;
        }
        __syncthreads();
#pragma unroll
        for (int kk = 0; kk < BK; ++kk) {
            float a[4], b[4];
#pragma unroll
            for (int i = 0; i < 4; ++i) a[i] = sA[kk][ty * 4 + i];
#pragma unroll
            for (int j = 0; j < 4; ++j) b[j] = sB[kk][tx * 4 + j];
#pragma unroll
            for (int i = 0; i < 4; ++i)
#pragma unroll
                for (int j = 0; j < 4; ++j) acc[i][j] += a[i] * b[j];
        }
        __syncthreads();
    }
#pragma unroll
    for (int i = 0; i < 4; ++i) {
        const int o = ot + ty * 4 + i;
        const float cv = cvec[n * C + o];
        float4 v;
        v.x = acc[i][0] + cv; v.y = acc[i][1] + cv;
        v.z = acc[i][2] + cv; v.w = acc[i][3] + cv;
        *(float4*)&pout[((size_t)n * C + o) * HW + tt + tx * 4] = v;
    }
}

// ---------------------------------------------------------------------------
// K6: per-channel BN stats -> scale/shift directly. grid 256 (one per o).
__global__ __launch_bounds__(256) void k_bnstat(const float* __restrict__ p,
        const float* __restrict__ gamma, const float* __restrict__ beta,
        float* __restrict__ scale, float* __restrict__ shift) {
    const int o = blockIdx.x;
    float s0 = 0.f, s1 = 0.f;
    for (int n = 0; n < NB; ++n) {
        const float4* pp = (const float4*)(p + ((size_t)n * C + o) * HW);
        for (int i = threadIdx.x; i < HW / 4; i += 256) {
            const float4 v = pp[i];
            s0 += v.x + v.y + v.z + v.w;
            s1 += v.x * v.x + v.y * v.y + v.z * v.z + v.w * v.w;
        }
    }
    for (int off = 32; off; off >>= 1) {
        s0 += __shfl_down(s0, off, 64);
        s1 += __shfl_down(s1, off, 64);
    }
    __shared__ float r0[4], r1[4];
    if ((threadIdx.x & 63) == 0) { r0[threadIdx.x >> 6] = s0; r1[threadIdx.x >> 6] = s1; }
    __syncthreads();
    if (threadIdx.x == 0) {
        const float S0 = r0[0] + r0[1] + r0[2] + r0[3];
        const float S1 = r1[0] + r1[1] + r1[2] + r1[3];
        const float mean = S0 * (1.f / (float)NHW);
        const float var  = S1 * (1.f / (float)NHW) - mean * mean;
        const float sc   = gamma[o] * rsqrtf(var + 1e-5f);
        scale[o] = sc;
        shift[o] = beta[o] - mean * sc;
    }
}

// ---------------------------------------------------------------------------
// K7: out = x + scale[c]*p + shift[c]   (in-place on d_out which holds p)
__global__ __launch_bounds__(256) void k_final(const float* __restrict__ x,
        float* __restrict__ out, const float* __restrict__ scale,
        const float* __restrict__ shift) {
    const size_t total4 = (size_t)NB * C * HW / 4;
    size_t i = (size_t)blockIdx.x * 256 + threadIdx.x;
    const size_t stride = (size_t)gridDim.x * 256;
    for (; i < total4; i += stride) {
        const int c = (int)((i >> 10) & 255);
        const float sc = scale[c], sh = shift[c];
        const float4 xv = ((const float4*)x)[i];
        const float4 pv = ((float4*)out)[i];
        float4 r;
        r.x = xv.x + sc * pv.x + sh;
        r.y = xv.y + sc * pv.y + sh;
        r.z = xv.z + sc * pv.z + sh;
        r.w = xv.w + sc * pv.w + sh;
        ((float4*)out)[i] = r;
    }
}

// ---------------------------------------------------------------------------
extern "C" void kernel_launch(void* const* d_in, const int* in_sizes, int n_in,
                              void* d_out, int out_size, void* d_ws, size_t ws_size,
                              hipStream_t stream) {
    const float* x       = (const float*)d_in[0];
    const float* w_theta = (const float*)d_in[1];
    const float* b_theta = (const float*)d_in[2];
    const float* w_phi   = (const float*)d_in[3];
    const float* b_phi   = (const float*)d_in[4];
    const float* w_g     = (const float*)d_in[6 - 1]; // w_g is input 5
    const float* b_g     = (const float*)d_in[6];
    const float* w_out   = (const float*)d_in[7];
    const float* b_out   = (const float*)d_in[8];
    const float* gamma   = (const float*)d_in[9];
    const float* beta    = (const float*)d_in[10];
    float* out = (float*)d_out;
    float* ws  = (float*)d_ws;

    // workspace layout (float offsets)
    float* s     = ws;                       // 8192
    float* th    = s + NB * C;               // 4096
    float* ph    = th + NB * CI;             // 4096
    float* pm    = ph + NB * CI;             // 64
    float* A     = pm + NB * 2;              // 524288
    float* q     = A + (size_t)NB * CI * CI; // 4096
    float* W     = q + NB * CI;              // 1048576
    float* M     = W + (size_t)NB * C * CI;  // 2097152
    float* cvec  = M + (size_t)NB * C * C;   // 8192
    float* scale = cvec + NB * C;            // 256
    float* shift = scale + C;                // 256
    unsigned short* Mb16 = (unsigned short*)(shift + C);          // 2097152 u16
    unsigned short* xT   = (unsigned short*)(shift + C) + (size_t)NB * C * C; // 33554432 u16
    const size_t need_bytes =
        ((char*)(xT + (size_t)NB * HW * C) - (char*)ws);
    const bool use_mfma = (ws_size >= need_bytes);

    hipMemsetAsync(s, 0, NB * C * sizeof(float), stream);
    if (use_mfma) {
        k_prep<<<dim3(64, 4, NB), 256, 0, stream>>>(x, xT, s);
    } else {
        // channel sums only (reuse k_prep would need xT space) — use bnstat-free path:
        // fall back to a tiny sum kernel via k_prep's logic is unavailable; do it inline:
        // one block per (n,c): simple reduction
        // (defined below as k_colsum)
        extern __global__ void k_colsum(const float*, float*);
        k_colsum<<<NB * C, 256, 0, stream>>>(x, s);
    }
    k_thph<<<NB, CI, 0, stream>>>(s, w_theta, b_theta, w_phi, b_phi, th, ph, pm);
    k_arow<<<NB * CI, 64, 0, stream>>>(th, ph, pm, b_g, A, q);
    k_W<<<NB * C, CI, 0, stream>>>(w_out, A, q, b_out, W, cvec);
    k_M<<<NB * C, C, 0, stream>>>(W, w_g, M, use_mfma ? Mb16 : (unsigned short*)M);
    if (use_mfma) {
        k_gemm_mfma<<<dim3(64, NB), 256, 0, stream>>>(xT, Mb16, cvec, out);
    } else {
        k_gemm_f32<<<dim3(256, NB), 256, 0, stream>>>(x, M, cvec, out);
    }
    k_bnstat<<<C, 256, 0, stream>>>(out, gamma, beta, scale, shift);
    k_final<<<32768, 256, 0, stream>>>(x, out, scale, shift);
}

// fallback channel-sum kernel (only used when ws is too small for xT)
__global__ __launch_bounds__(256) void k_colsum(const float* __restrict__ x,
                                                float* __restrict__ s) {
    const int bc = blockIdx.x;
    const float4* p4 = (const float4*)(x + (size_t)bc * HW);
    const int tid = threadIdx.x;
    float acc = 0.f;
    for (int i = tid; i < HW / 4; i += 256) {
        const float4 v = p4[i];
        acc += v.x + v.y + v.z + v.w;
    }
    for (int off = 32; off; off >>= 1) acc += __shfl_down(acc, off, 64);
    __shared__ float red[4];
    if ((tid & 63) == 0) red[tid >> 6] = acc;
    __syncthreads();
    if (tid == 0) atomicAdd(&s[bc], red[0] + red[1] + red[2] + red[3]);
}